// Round 2
// 694.584 us; speedup vs baseline: 1.0146x; 1.0146x over previous
//
#include <hip/hip_runtime.h>

#define BB 8
#define NF 128
#define EE 3072
#define UU 4096
#define UBITS 12
#define MAXS 32

// ws layout (no poison dependence; k_prep zero-inits counts):
//   counts[BB*UU]        u32  - atomic counters, zeroed by k_prep
//   colmap[BB*UU]        i32  - feature column for valid dst slot, -1 otherwise
//   slots[BB*MAXS*UU]    u32  - per-(b,u) source-column lists
//   ftT[BB*EE*NF]        f32  - feats transposed to [B, E, NF] (contiguous n!)

// ---------------------------------------------------------------------------
// Prep: one block per batch. Runtime dtype-detect (int32 vs byte bools) from
// the first 4 KB of dst -- in-bounds under BOTH layouts, exact test: int32
// bool words are only 0/1; packed bytes at 75% density give words > 1.
// (Host-side in_sizes proved unreliable for dtype in R1 -- absmax 12.0.)
// Then exclusive prefix-popcount of dst[b][:] -> per-slot feature column,
// computed ONCE here instead of once per scan block. Also zeroes counts.
__global__ __launch_bounds__(256) void k_prep(const void* __restrict__ dst,
                                              int* __restrict__ colmap,
                                              unsigned* __restrict__ counts) {
    const int b = blockIdx.x;
    const int tid = threadIdx.x;
    __shared__ int s_byte;
    __shared__ int part[256];
    if (tid == 0) s_byte = 0;
    __syncthreads();

    {
        const unsigned* w32 = (const unsigned*)dst;
        unsigned mx = 0;
#pragma unroll
        for (int k = 0; k < 4; ++k) mx |= w32[tid * 4 + k];
        if (mx > 1u) atomicOr(&s_byte, 1);
    }
    __syncthreads();
    const bool asbyte = (s_byte != 0);

    const int base_i = tid * 16;
    int f[16];
    if (asbyte) {
        const unsigned char* p = (const unsigned char*)dst + (size_t)b * UU + base_i;
#pragma unroll
        for (int i = 0; i < 16; ++i) f[i] = p[i] ? 1 : 0;
    } else {
        const int* p = (const int*)dst + (size_t)b * UU + base_i;
#pragma unroll
        for (int i = 0; i < 16; ++i) f[i] = p[i] ? 1 : 0;
    }
    int s = 0;
#pragma unroll
    for (int i = 0; i < 16; ++i) s += f[i];
    part[tid] = s;
    __syncthreads();
    // Hillis-Steele inclusive scan over the 256 partials
    for (int off = 1; off < 256; off <<= 1) {
        const int v = part[tid];
        const int w = (tid >= off) ? part[tid - off] : 0;
        __syncthreads();
        part[tid] = v + w;
        __syncthreads();
    }
    int run = tid ? part[tid - 1] : 0;
#pragma unroll
    for (int i = 0; i < 16; ++i) {
        const int c = run < (EE - 1) ? run : (EE - 1);   // clip like reference
        colmap[b * UU + base_i + i] = f[i] ? c : -1;
        run += f[i];
        counts[b * UU + base_i + i] = 0u;
    }
}

// ---------------------------------------------------------------------------
// Transpose feats [B,NF,E] -> ftT [B,E,NF] so emit can gather a column's
// 128 n-values with contiguous float4 loads (1 cache line per slot instead
// of 4 lines 393 KB apart). 12.6 MB each way -> ~5 us.
__global__ __launch_bounds__(256) void k_tr(const float* __restrict__ feats,
                                            float* __restrict__ ftT) {
    __shared__ float tile[32][33];
    const int b = blockIdx.z;
    const int e0 = blockIdx.x * 32;
    const int n0 = blockIdx.y * 32;
    const int tx = threadIdx.x & 31;
    const int ty = threadIdx.x >> 5;            // 0..7
#pragma unroll
    for (int r = 0; r < 4; ++r) {
        const int n = n0 + ty + 8 * r;
        tile[ty + 8 * r][tx] = feats[((size_t)(b * NF + n)) * EE + e0 + tx];
    }
    __syncthreads();
#pragma unroll
    for (int r = 0; r < 4; ++r) {
        const int e = e0 + ty + 8 * r;
        ftT[((size_t)(b * EE + e)) * NF + n0 + tx] = tile[tx][ty + 8 * r];
    }
}

// ---------------------------------------------------------------------------
// Scan: grid (UU/4, BB). Pure streaming: validity + column come from colmap
// (uniform L2 broadcast loads), no per-block dtype detect, no prefix
// recompute, no LDS reduction. Reads only valid rows (fully coalesced).
__global__ __launch_bounds__(256) void k_scan(const float4* __restrict__ um,
                                              const int* __restrict__ colmap,
                                              unsigned* __restrict__ counts,
                                              unsigned* __restrict__ slots) {
    const int b = blockIdx.y;
    const int v0 = blockIdx.x * 4;
    const int tid = threadIdx.x;

    int col[4];
#pragma unroll
    for (int h = 0; h < 4; ++h) col[h] = colmap[b * UU + v0 + h];
    if (col[0] < 0 && col[1] < 0 && col[2] < 0 && col[3] < 0) return;

    const float4* rowb = um + ((size_t)b << 22);

    float4 r[4][4];
#pragma unroll
    for (int h = 0; h < 4; ++h) {
        if (col[h] >= 0) {                       // wave-uniform branch
            const float4* row = rowb + ((size_t)(v0 + h) << 10);
#pragma unroll
            for (int k = 0; k < 4; ++k) r[h][k] = row[tid + k * 256];
        }
    }
#pragma unroll
    for (int h = 0; h < 4; ++h) {
        if (col[h] < 0) continue;
#pragma unroll
        for (int k = 0; k < 4; ++k) {
            const float4 v4 = r[h][k];
            if (v4.x == 0.f && v4.y == 0.f && v4.z == 0.f && v4.w == 0.f) continue;
            const int ubase = (tid + k * 256) << 2;
            const float vals[4] = {v4.x, v4.y, v4.z, v4.w};
#pragma unroll
            for (int e = 0; e < 4; ++e) {
                if (vals[e] != 0.f) {
                    const int uk = ubase + e;
                    const unsigned j = atomicAdd(&counts[b * UU + uk], 1u);
                    if (j < MAXS) slots[((size_t)b * MAXS + j) * UU + uk] = (unsigned)col[h];
                }
            }
        }
    }
}

// ---------------------------------------------------------------------------
// Emit: one thread per (b, u, 8-row n-group). Per slot j: ONE address ->
// two contiguous float4 loads (32 B of one cache line) instead of 4 scalar
// loads into 4 distant rows. counts/slots/occ reads stay fully coalesced.
__global__ __launch_bounds__(256) void k_emit(const float4* __restrict__ ftT4,
                                              const float* __restrict__ occ,
                                              const unsigned* __restrict__ counts,
                                              const unsigned* __restrict__ slots,
                                              float* __restrict__ out) {
    const int t = blockIdx.x * blockDim.x + threadIdx.x;   // < BB*(NF/8)*UU = 524288
    const int u = t & (UU - 1);
    const int g = t >> UBITS;                // b*16 + q, q in 0..15
    const int b = g >> 4;
    const int n0 = (g & 15) * 8;

    int c = (int)counts[b * UU + u];
    if (c > MAXS) c = MAXS;
    const float inv = 1.0f / occ[b * UU + u];

    const float4* fb = ftT4 + ((size_t)b * EE) * (NF / 4) + (n0 >> 2);
    float4 s0 = make_float4(0.f, 0.f, 0.f, 0.f);
    float4 s1 = make_float4(0.f, 0.f, 0.f, 0.f);
    for (int j = 0; j < c; ++j) {
        const int col = (int)slots[((size_t)b * MAXS + j) * UU + u];
        const float4* p = fb + (size_t)col * (NF / 4);
        const float4 f0 = p[0];
        const float4 f1 = p[1];
        s0.x += f0.x; s0.y += f0.y; s0.z += f0.z; s0.w += f0.w;
        s1.x += f1.x; s1.y += f1.y; s1.z += f1.z; s1.w += f1.w;
    }
    float* ob = out + ((size_t)(b * NF + n0)) * UU + u;
    const float v[8] = {s0.x, s0.y, s0.z, s0.w, s1.x, s1.y, s1.z, s1.w};
#pragma unroll
    for (int i = 0; i < 8; ++i) ob[(size_t)i * UU] = v[i] * inv;
}

// ---------------------------------------------------------------------------
extern "C" void kernel_launch(void* const* d_in, const int* in_sizes, int n_in,
                              void* d_out, int out_size, void* d_ws, size_t ws_size,
                              hipStream_t stream) {
    const float* feats = (const float*)d_in[0];   // [B, NF, E]
    const float* um    = (const float*)d_in[1];   // [B, U, U]
    const float* occ   = (const float*)d_in[2];   // [B, 1, U]
    const void*  dst   = d_in[3];                 // [B, U] bool/int (runtime-detected)

    float* out = (float*)d_out;                   // [B, NF, U]

    unsigned* counts = (unsigned*)d_ws;
    int*      colmap = (int*)(counts + BB * UU);
    unsigned* slots  = (unsigned*)(colmap + BB * UU);
    float*    ftT    = (float*)(slots + (size_t)BB * MAXS * UU);

    k_prep<<<dim3(BB), 256, 0, stream>>>(dst, colmap, counts);
    k_tr<<<dim3(EE / 32, NF / 32, BB), 256, 0, stream>>>(feats, ftT);
    k_scan<<<dim3(UU / 4, BB), 256, 0, stream>>>((const float4*)um, colmap,
                                                 counts, slots);
    const int n_emit = BB * (NF / 8) * UU;        // 524,288 threads
    k_emit<<<n_emit / 256, 256, 0, stream>>>((const float4*)ftT, occ,
                                             counts, slots, out);
}